// Round 7
// baseline (852.784 us; speedup 1.0000x reference)
//
#include <hip/hip_runtime.h>
#include <cstdint>
#include <cstddef>

namespace {

constexpr int kN    = 100000;  // nodes per type (N_REQ == N_CODE)
constexpr int kNpad = 100096;  // 782*128, GEMM tile-padded row count
constexpr int kE    = 500000;  // edges per direction
constexpr int kEL   = 200000;  // label edges
constexpr int kC    = 256;     // channels
constexpr int kH    = 8;       // heads
constexpr float kNegSlope = 0.2f;
constexpr float kBnEps    = 1e-5f;

typedef float    f32x4  __attribute__((ext_vector_type(4)));
typedef __bf16   bf16x8 __attribute__((ext_vector_type(8)));
typedef _Float16 h4     __attribute__((ext_vector_type(4)));

__device__ inline unsigned short bf16_rtn(float x) {
  unsigned u = __builtin_bit_cast(unsigned, x);
  unsigned r = (u + 0x7fffu + ((u >> 16) & 1u)) >> 16;
  return (unsigned short)r;
}
__device__ inline float bf16_f(unsigned short h) {
  unsigned u = ((unsigned)h) << 16;
  return __builtin_bit_cast(float, u);
}

// ------------- zero-fill (graph-capture-safe), two arrays in one dispatch -------------
__global__ void zero2_kernel(int* __restrict__ p0, int* __restrict__ p1, int n) {
  const int i = blockIdx.x * 256 + threadIdx.x;
  if (i < n) {
    p0[i] = 0;
    p1[i] = 0;
  }
}

// ------------- fp32 -> split bf16 (hi/lo) conversion (weights only) -------------
__global__ __launch_bounds__(256) void cvt_kernel(
    const float* __restrict__ in, unsigned short* __restrict__ hi,
    unsigned short* __restrict__ lo, int n4) {
  const int i = blockIdx.x * 256 + threadIdx.x;
  if (i >= n4) return;
  const float4 v = ((const float4*)in)[i];
  const unsigned short h0 = bf16_rtn(v.x), h1 = bf16_rtn(v.y),
                       h2 = bf16_rtn(v.z), h3 = bf16_rtn(v.w);
  ((ushort4*)hi)[i] = make_ushort4(h0, h1, h2, h3);
  ((ushort4*)lo)[i] = make_ushort4(bf16_rtn(v.x - bf16_f(h0)),
                                   bf16_rtn(v.y - bf16_f(h1)),
                                   bf16_rtn(v.z - bf16_f(h2)),
                                   bf16_rtn(v.w - bf16_f(h3)));
}

// ------------- fused GEMM: H[M,256] = X @ W^T + b, fp16 out, BOTH node types ---------
// LDS-FREE / BARRIER-FREE. History: R5 (LDS-staged, 2 barriers/kt): 191 us,
// MfmaUtil 17%, HBM 22%, all pipes idle; R6 (dbuf, 1 barrier/kt): 213 us --
// the barrier's vmcnt(0) drain defeats source-level pipelining (guide m99/m131).
// Here both operand fragments are loaded straight to registers:
//   A: each lane loads ITS OWN 8 consecutive fp32 of X (16 rows x 128B per
//      instruction, coalesced) and splits hi/lo in-register via (__bf16) casts
//      (hardware RTNE == bf16_rtn bit-exactly on finite values).
//   B: weights are 0.5 MB, L2-resident across all 3128 blocks; fragments are
//      16B/lane contiguous (16 rows x 64B per instruction).
// No LDS round-trip, no __syncthreads -> waves are independent dataflow and
// the compiler pipelines loads/cvt/MFMA across kt freely.
__global__ __launch_bounds__(256) void gemm_fused_kernel(
    const float* __restrict__ X0, const float* __restrict__ X1,
    const unsigned short* __restrict__ Whi0, const unsigned short* __restrict__ Wlo0,
    const unsigned short* __restrict__ Whi1, const unsigned short* __restrict__ Wlo1,
    const float* __restrict__ bias0, const float* __restrict__ bias1,
    _Float16* __restrict__ H0, _Float16* __restrict__ H1) {
  const bool t1 = (blockIdx.z != 0);
  const float* __restrict__ X            = t1 ? X1 : X0;
  const unsigned short* __restrict__ Whi = t1 ? Whi1 : Whi0;
  const unsigned short* __restrict__ Wlo = t1 ? Wlo1 : Wlo0;
  const float* __restrict__ bias         = t1 ? bias1 : bias0;
  _Float16* __restrict__ H               = t1 ? H1 : H0;

  const int tid  = threadIdx.x;
  const int m0   = blockIdx.y * 128;
  const int n0   = blockIdx.x * 128;
  const int w    = tid >> 6, lane = tid & 63, l16 = lane & 15, quad = lane >> 4;
  const int wm   = (w >> 1) * 64, wn = (w & 1) * 64;

  // Per-thread operand rows (fixed across the K loop).
  // A rows clamped for the 96-row pad tail (stores masked in epilogue).
  int arow[4], brow[4];
#pragma unroll
  for (int mi = 0; mi < 4; ++mi) arow[mi] = min(m0 + wm + mi * 16 + l16, kN - 1);
#pragma unroll
  for (int ni = 0; ni < 4; ++ni) brow[ni] = wn + ni * 16 + l16;  // < 128; +n0 below

  f32x4 acc[4][4] = {};

  for (int kt = 0; kt < kC / 32; ++kt) {
    const int k0 = kt * 32 + quad * 8;  // this lane's 8-elem K-slice

    bf16x8 ah[4], al[4], bh[4], bl[4];
#pragma unroll
    for (int mi = 0; mi < 4; ++mi) {
      const float* xp = &X[(size_t)arow[mi] * kC + k0];
      const f32x4 x0 = *(const f32x4*)xp;
      const f32x4 x1 = *(const f32x4*)(xp + 4);
#pragma unroll
      for (int j = 0; j < 4; ++j) {
        const __bf16 h0 = (__bf16)x0[j];
        const __bf16 h1 = (__bf16)x1[j];
        ah[mi][j]     = h0;
        ah[mi][j + 4] = h1;
        al[mi][j]     = (__bf16)(x0[j] - (float)h0);
        al[mi][j + 4] = (__bf16)(x1[j] - (float)h1);
      }
    }
#pragma unroll
    for (int ni = 0; ni < 4; ++ni) {
      const size_t boff = (size_t)(n0 + brow[ni]) * kC + k0;
      bh[ni] = *(const bf16x8*)&Whi[boff];
      bl[ni] = *(const bf16x8*)&Wlo[boff];
    }

#pragma unroll
    for (int mi = 0; mi < 4; ++mi)
#pragma unroll
      for (int ni = 0; ni < 4; ++ni) {
        acc[mi][ni] = __builtin_amdgcn_mfma_f32_16x16x32_bf16(ah[mi], bh[ni], acc[mi][ni], 0, 0, 0);
        acc[mi][ni] = __builtin_amdgcn_mfma_f32_16x16x32_bf16(ah[mi], bl[ni], acc[mi][ni], 0, 0, 0);
        acc[mi][ni] = __builtin_amdgcn_mfma_f32_16x16x32_bf16(al[mi], bh[ni], acc[mi][ni], 0, 0, 0);
      }
  }

  // epilogue: D[row=quad*4+r][col=l16] per 16x16 tile; +bias, fp16 store
#pragma unroll
  for (int ni = 0; ni < 4; ++ni) {
    const int col = n0 + wn + ni * 16 + l16;
    const float bc = bias[col];
#pragma unroll
    for (int mi = 0; mi < 4; ++mi) {
      const int gm0 = m0 + wm + mi * 16 + quad * 4;
#pragma unroll
      for (int r = 0; r < 4; ++r) {
        const int gm = gm0 + r;
        if (gm < kN) H[(size_t)gm * kC + col] = (_Float16)(acc[mi][ni][r] + bc);
      }
    }
  }
}

// ------------- per-node attention scalars: a[n,h] = <h[n,h,:], att[h,:]> -------------
__global__ __launch_bounds__(256) void avec_kernel(
    const _Float16* __restrict__ h, const float* __restrict__ attA,
    const float* __restrict__ attB, float* __restrict__ outA,
    float* __restrict__ outB, int N) {
  const int n = blockIdx.x * 4 + (threadIdx.x >> 6);
  if (n >= N) return;
  const int L = threadIdx.x & 63;
  const h4 hv = *(const h4*)&h[(size_t)n * kC + 4 * L];
  const float4 a = *(const float4*)&attA[4 * L];
  const float4 b = *(const float4*)&attB[4 * L];
  const float hx = (float)hv.x, hy = (float)hv.y, hz = (float)hv.z, hw = (float)hv.w;
  float pa = hx * a.x + hy * a.y + hz * a.z + hw * a.w;
  float pb = hx * b.x + hy * b.y + hz * b.z + hw * b.w;
  for (int m = 1; m < 8; m <<= 1) {
    pa += __shfl_xor(pa, m);
    pb += __shfl_xor(pb, m);
  }
  if ((L & 7) == 0) {
    outA[n * kH + (L >> 3)] = pa;
    outB[n * kH + (L >> 3)] = pb;
  }
}

// ------------- CSR build -------------
__global__ void count_kernel(const int* __restrict__ dst, int E, int* __restrict__ cnt) {
  const int e = blockIdx.x * 256 + threadIdx.x;
  if (e < E) atomicAdd(&cnt[dst[e]], 1);
}

__global__ void scan1_kernel(const int* __restrict__ cnt, int N,
                             int* __restrict__ off, int* __restrict__ part) {
  __shared__ int s[256];
  const int t = threadIdx.x;
  const int i = blockIdx.x * 256 + t;
  const int v = (i < N) ? cnt[i] : 0;
  s[t] = v;
  __syncthreads();
  for (int o = 1; o < 256; o <<= 1) {
    const int x = (t >= o) ? s[t - o] : 0;
    __syncthreads();
    s[t] += x;
    __syncthreads();
  }
  if (i < N) off[i] = s[t] - v;
  if (t == 255) part[blockIdx.x] = s[255];
}

__global__ void scan2_kernel(int* __restrict__ part, int NB) {  // one block, 512 thr
  __shared__ int s[512];
  const int t = threadIdx.x;
  const int v = (t < NB) ? part[t] : 0;
  s[t] = v;
  __syncthreads();
  for (int o = 1; o < 512; o <<= 1) {
    const int x = (t >= o) ? s[t - o] : 0;
    __syncthreads();
    s[t] += x;
    __syncthreads();
  }
  if (t < NB) part[t] = s[t] - v;
}

__global__ void scan3_kernel(int* __restrict__ off, int* __restrict__ cur,
                             const int* __restrict__ part, int N) {
  const int i = blockIdx.x * 256 + threadIdx.x;
  if (i < N) {
    const int v = off[i] + part[blockIdx.x];
    off[i] = v;
    cur[i] = v;
  }
}

// stores the SOURCE NODE ID (not the edge id) at the dst-sorted slot:
// aggregate then needs one less dependent indirection per edge.
__global__ void scatter_kernel(const int* __restrict__ dst,
                               const int* __restrict__ srcv, int E,
                               int* __restrict__ cur, int* __restrict__ perm) {
  const int e = blockIdx.x * 256 + threadIdx.x;
  if (e < E) {
    const int p = atomicAdd(&cur[dst[e]], 1);
    perm[p] = srcv[e];
  }
}

// ------------- fused segment-softmax + weighted aggregate + relu -------------
// Both edge directions in ONE dispatch (blockIdx.y selects), 4-way unrolled
// edge loop for memory-level parallelism. (Round-4 counters: 118.8 us,
// 4350 GB/s = 54% peak, VALU 50%, occ 71% -- mixed BW/VALU regime.)
__global__ __launch_bounds__(256) void aggregate2_kernel(
    const _Float16* __restrict__ h0, const float* __restrict__ aS0,
    const float* __restrict__ aD0, const int* __restrict__ srcs0,
    const int* __restrict__ off0, const int* __restrict__ cnt0,
    float* __restrict__ out0,
    const _Float16* __restrict__ h1, const float* __restrict__ aS1,
    const float* __restrict__ aD1, const int* __restrict__ srcs1,
    const int* __restrict__ off1, const int* __restrict__ cnt1,
    float* __restrict__ out1) {
  const int d = blockIdx.x * 4 + (threadIdx.x >> 6);
  if (d >= kN) return;
  const bool dir1 = (blockIdx.y != 0);
  const _Float16* __restrict__ hsrc = dir1 ? h1 : h0;
  const float* __restrict__ aS   = dir1 ? aS1 : aS0;
  const float* __restrict__ aD   = dir1 ? aD1 : aD0;
  const int* __restrict__ srcs   = dir1 ? srcs1 : srcs0;
  const int* __restrict__ off    = dir1 ? off1 : off0;
  const int* __restrict__ cnt    = dir1 ? cnt1 : cnt0;
  float* __restrict__ out        = dir1 ? out1 : out0;

  const int L  = threadIdx.x & 63;
  const int hd = L >> 3;  // lane's 4 channels all in head L>>3
  const float ad = aD[d * kH + hd];
  const int o = off[d], c = cnt[d];
  float4 acc = make_float4(0.f, 0.f, 0.f, 0.f);
  float se = 0.f;
  int i = 0;
  for (; i + 4 <= c; i += 4) {
    // 4 independent src ids (contiguous, cache-hot) ...
    const int s0 = srcs[o + i], s1 = srcs[o + i + 1];
    const int s2 = srcs[o + i + 2], s3 = srcs[o + i + 3];
    // ... then 4 independent scalar gathers + 4 independent row gathers
    const float a0 = aS[s0 * kH + hd], a1 = aS[s1 * kH + hd];
    const float a2 = aS[s2 * kH + hd], a3 = aS[s3 * kH + hd];
    const h4 v0 = *(const h4*)&hsrc[(size_t)s0 * kC + 4 * L];
    const h4 v1 = *(const h4*)&hsrc[(size_t)s1 * kC + 4 * L];
    const h4 v2 = *(const h4*)&hsrc[(size_t)s2 * kC + 4 * L];
    const h4 v3 = *(const h4*)&hsrc[(size_t)s3 * kC + 4 * L];
    float t0 = a0 + ad; t0 = t0 > 0.f ? t0 : kNegSlope * t0;
    float t1 = a1 + ad; t1 = t1 > 0.f ? t1 : kNegSlope * t1;
    float t2 = a2 + ad; t2 = t2 > 0.f ? t2 : kNegSlope * t2;
    float t3 = a3 + ad; t3 = t3 > 0.f ? t3 : kNegSlope * t3;
    const float w0 = __expf(t0), w1 = __expf(t1);
    const float w2 = __expf(t2), w3 = __expf(t3);
    se += (w0 + w1) + (w2 + w3);
    acc.x += w0 * (float)v0.x + w1 * (float)v1.x + w2 * (float)v2.x + w3 * (float)v3.x;
    acc.y += w0 * (float)v0.y + w1 * (float)v1.y + w2 * (float)v2.y + w3 * (float)v3.y;
    acc.z += w0 * (float)v0.z + w1 * (float)v1.z + w2 * (float)v2.z + w3 * (float)v3.z;
    acc.w += w0 * (float)v0.w + w1 * (float)v1.w + w2 * (float)v2.w + w3 * (float)v3.w;
  }
  for (; i < c; ++i) {
    const int s = srcs[o + i];
    float t = aS[s * kH + hd] + ad;
    t = t > 0.f ? t : kNegSlope * t;
    const float wgt = __expf(t);
    se += wgt;
    const h4 hv = *(const h4*)&hsrc[(size_t)s * kC + 4 * L];
    acc.x += wgt * (float)hv.x;
    acc.y += wgt * (float)hv.y;
    acc.z += wgt * (float)hv.z;
    acc.w += wgt * (float)hv.w;
  }
  const float inv = 1.f / (se + 1e-16f);
  float4 r;
  r.x = fmaxf(acc.x * inv, 0.f);
  r.y = fmaxf(acc.y * inv, 0.f);
  r.z = fmaxf(acc.z * inv, 0.f);
  r.w = fmaxf(acc.w * inv, 0.f);
  *(float4*)&out[(size_t)d * kC + 4 * L] = r;
}

// ------------- BatchNorm stats (biased var), two-stage: NO global atomics -------------
constexpr int kBnB = 512;  // blocks per tensor
__global__ __launch_bounds__(256) void bn_stats_kernel(
    const float* __restrict__ xr, const float* __restrict__ xc,
    float* __restrict__ part) {
  __shared__ f32x4 red[2][4][64];
  const float* __restrict__ x = blockIdx.y ? xc : xr;
  const int t = threadIdx.x, w = t >> 6, L = t & 63;
  const int rowsPer = (kN + kBnB - 1) / kBnB;  // 196
  const int r0 = blockIdx.x * rowsPer;
  const int r1 = min(r0 + rowsPer, kN);
  f32x4 s0 = {0.f, 0.f, 0.f, 0.f}, q0 = {0.f, 0.f, 0.f, 0.f};
  f32x4 s1 = {0.f, 0.f, 0.f, 0.f}, q1 = {0.f, 0.f, 0.f, 0.f};
  f32x4 s2 = {0.f, 0.f, 0.f, 0.f}, q2 = {0.f, 0.f, 0.f, 0.f};
  f32x4 s3 = {0.f, 0.f, 0.f, 0.f}, q3 = {0.f, 0.f, 0.f, 0.f};
  int r = r0 + w;
  for (; r + 12 < r1; r += 16) {  // 4 independent loads issued back-to-back
    const f32x4 v0 = *(const f32x4*)&x[(size_t)(r)      * kC + 4 * L];
    const f32x4 v1 = *(const f32x4*)&x[(size_t)(r + 4)  * kC + 4 * L];
    const f32x4 v2 = *(const f32x4*)&x[(size_t)(r + 8)  * kC + 4 * L];
    const f32x4 v3 = *(const f32x4*)&x[(size_t)(r + 12) * kC + 4 * L];
    s0 += v0; q0 += v0 * v0;
    s1 += v1; q1 += v1 * v1;
    s2 += v2; q2 += v2 * v2;
    s3 += v3; q3 += v3 * v3;
  }
  for (; r < r1; r += 4) {
    const f32x4 v = *(const f32x4*)&x[(size_t)r * kC + 4 * L];
    s0 += v; q0 += v * v;
  }
  const f32x4 s = (s0 + s1) + (s2 + s3);
  const f32x4 q = (q0 + q1) + (q2 + q3);
  red[0][w][L] = s;
  red[1][w][L] = q;
  __syncthreads();
  if (w == 0) {
    const f32x4 ts = red[0][0][L] + red[0][1][L] + red[0][2][L] + red[0][3][L];
    const f32x4 t2 = red[1][0][L] + red[1][1][L] + red[1][2][L] + red[1][3][L];
    float* dst = part + ((size_t)blockIdx.y * kBnB + blockIdx.x) * 512;
    *(f32x4*)&dst[4 * L]       = ts;
    *(f32x4*)&dst[256 + 4 * L] = t2;
  }
}

// Stage 2: reduce kBnB partials per channel, fold into per-channel scale/bias.
__global__ __launch_bounds__(256) void bn_final_kernel(
    const float* __restrict__ part, const float* __restrict__ gamma,
    const float* __restrict__ beta, float* __restrict__ sb) {
  const int c = threadIdx.x;
  const int t = blockIdx.x;
  const float* __restrict__ p0 = part + (size_t)t * kBnB * 512;
  float s = 0.f, q = 0.f;
#pragma unroll 4
  for (int b = 0; b < kBnB; ++b) {
    s += p0[b * 512 + c];
    q += p0[b * 512 + 256 + c];
  }
  const float mu  = s * (1.f / kN);
  const float var = q * (1.f / kN) - mu * mu;
  const float sc  = gamma[c] * rsqrtf(var + kBnEps);
  sb[t * 512 + c]       = sc;
  sb[t * 512 + 256 + c] = beta[c] - mu * sc;
}

// ------------- edge classifier: sigmoid(<z_req[i], z_code[j]>), BN fused -------------
__global__ __launch_bounds__(256) void classify_kernel(
    const float* __restrict__ zr, const float* __restrict__ zc,
    const int* __restrict__ ei, const int* __restrict__ ej,
    const float* __restrict__ sb, float* __restrict__ y, int EL) {
  const int e = blockIdx.x * 4 + (threadIdx.x >> 6);
  if (e >= EL) return;
  const int L = threadIdx.x & 63;
  const int i = ei[e], j = ej[e];
  const float4 a  = *(const float4*)&zr[(size_t)i * kC + 4 * L];
  const float4 b  = *(const float4*)&zc[(size_t)j * kC + 4 * L];
  const float4 sr = *(const float4*)&sb[4 * L];
  const float4 br = *(const float4*)&sb[256 + 4 * L];
  const float4 sc = *(const float4*)&sb[512 + 4 * L];
  const float4 bc = *(const float4*)&sb[768 + 4 * L];
  float p = (a.x * sr.x + br.x) * (b.x * sc.x + bc.x) +
            (a.y * sr.y + br.y) * (b.y * sc.y + bc.y) +
            (a.z * sr.z + br.z) * (b.z * sc.z + bc.z) +
            (a.w * sr.w + br.w) * (b.w * sc.w + bc.w);
  for (int m = 1; m < 64; m <<= 1) p += __shfl_xor(p, m);
  if (L == 0) y[e] = 1.f / (1.f + __expf(-p));
}

}  // namespace

extern "C" void kernel_launch(void* const* d_in, const int* in_sizes, int n_in,
                              void* d_out, int out_size, void* d_ws, size_t ws_size,
                              hipStream_t stream) {
  (void)in_sizes; (void)n_in; (void)out_size; (void)ws_size;
  const float* x_req      = (const float*)d_in[0];
  const float* x_code     = (const float*)d_in[1];
  const int*   ei_rc      = (const int*)d_in[2];   // [src(E) | dst(E)] req -> code
  const int*   ei_cr      = (const int*)d_in[3];   // [src(E) | dst(E)] code -> req
  const int*   el         = (const int*)d_in[4];   // [req(EL) | code(EL)]
  const float* W_req      = (const float*)d_in[5];
  const float* b_req      = (const float*)d_in[6];
  const float* W_code     = (const float*)d_in[7];
  const float* b_code     = (const float*)d_in[8];
  const float* att_src_rc = (const float*)d_in[9];
  const float* att_dst_rc = (const float*)d_in[10];
  const float* att_src_cr = (const float*)d_in[11];
  const float* att_dst_cr = (const float*)d_in[12];
  // d_in[13..15] = k_W, k_b, q : semantic attn over ONE metapath == identity -> unused
  const float* gamma      = (const float*)d_in[16];
  const float* beta       = (const float*)d_in[17];
  float* y = (float*)d_out;

  // ---- workspace (~327 MB peak, layout unchanged from the passing round-3 run) ----
  char* p = (char*)d_ws;
  auto alloc = [&](size_t bytes) {
    char* r = p;
    p += (bytes + 1023) & ~(size_t)1023;
    return r;
  };
  // Xhi/Xlo region no longer used for X staging (GEMM reads fp32 inputs directly);
  // kept as the out_code scratch region (identical proven footprint).
  unsigned short* Xhi = (unsigned short*)alloc((size_t)kNpad * kC * 2);  // 51.25 MB
  unsigned short* Xlo = (unsigned short*)alloc((size_t)kNpad * kC * 2);  // 51.25 MB
  (void)Xlo;
  float* out_code = (float*)Xhi;  // needs 102.4 MB; region is 102.5 MB
  _Float16* h_req  = (_Float16*)alloc((size_t)kN * kC * 2);  // 51.2 MB
  _Float16* h_code = (_Float16*)alloc((size_t)kN * kC * 2);  // 51.2 MB
  float* out_req   = (float*)alloc((size_t)kN * kC * 4);     // 102.4 MB
  unsigned short* Whi_r = (unsigned short*)alloc((size_t)kC * kC * 2);
  unsigned short* Wlo_r = (unsigned short*)alloc((size_t)kC * kC * 2);
  unsigned short* Whi_c = (unsigned short*)alloc((size_t)kC * kC * 2);
  unsigned short* Wlo_c = (unsigned short*)alloc((size_t)kC * kC * 2);
  float* a_src_rc = (float*)alloc((size_t)kN * kH * 4);  // 3.2 MB
  float* a_dst_rc = (float*)alloc((size_t)kN * kH * 4);
  float* a_src_cr = (float*)alloc((size_t)kN * kH * 4);
  float* a_dst_cr = (float*)alloc((size_t)kN * kH * 4);
  int* cnt_rc  = (int*)alloc((size_t)kN * 4);
  int* off_rc  = (int*)alloc((size_t)kN * 4);
  int* cur_rc  = (int*)alloc((size_t)kN * 4);
  int* perm_rc = (int*)alloc((size_t)kE * 4);
  int* cnt_cr  = (int*)alloc((size_t)kN * 4);
  int* off_cr  = (int*)alloc((size_t)kN * 4);
  int* cur_cr  = (int*)alloc((size_t)kN * 4);
  int* perm_cr = (int*)alloc((size_t)kE * 4);
  int*   part  = (int*)alloc(512 * 4);
  // BN scratch aliases dead regions (proven in round 3):
  float* bnpart = (float*)a_src_rc;  // needs 2*kBnB*512*4 = 2,097,152 B (of 3.2 MB)
  float* sb     = (float*)a_src_cr;  // needs 4096 B

  const int nScanB = (kN + 255) / 256;  // 391
  const int nW4    = kC * kC / 4;       // 16384 float4

  zero2_kernel<<<nScanB, 256, 0, stream>>>(cnt_rc, cnt_cr, kN);

  // weight conversion (tiny, 0.25 MB each)
  cvt_kernel<<<(nW4 + 255) / 256, 256, 0, stream>>>(W_req, Whi_r, Wlo_r, nW4);
  cvt_kernel<<<(nW4 + 255) / 256, 256, 0, stream>>>(W_code, Whi_c, Wlo_c, nW4);

  // projections: both node types, one dispatch; LDS-free, barrier-free GEMM
  gemm_fused_kernel<<<dim3(kC / 128, kNpad / 128, 2), 256, 0, stream>>>(
      x_req, x_code, Whi_r, Wlo_r, Whi_c, Wlo_c, b_req, b_code, h_req, h_code);

  // attention scalars: req is src in rc / dst in cr; code is src in cr / dst in rc
  avec_kernel<<<(kN + 3) / 4, 256, 0, stream>>>(h_req, att_src_rc, att_dst_cr,
                                                a_src_rc, a_dst_cr, kN);
  avec_kernel<<<(kN + 3) / 4, 256, 0, stream>>>(h_code, att_src_cr, att_dst_rc,
                                                a_src_cr, a_dst_rc, kN);

  // CSR build (dst-sorted src-id arrays per direction)
  const int* src_rc = ei_rc;
  const int* dst_rc = ei_rc + kE;
  const int* src_cr = ei_cr;
  const int* dst_cr = ei_cr + kE;
  count_kernel<<<(kE + 255) / 256, 256, 0, stream>>>(dst_rc, kE, cnt_rc);
  count_kernel<<<(kE + 255) / 256, 256, 0, stream>>>(dst_cr, kE, cnt_cr);
  scan1_kernel<<<nScanB, 256, 0, stream>>>(cnt_rc, kN, off_rc, part);
  scan2_kernel<<<1, 512, 0, stream>>>(part, nScanB);
  scan3_kernel<<<nScanB, 256, 0, stream>>>(off_rc, cur_rc, part, kN);
  scan1_kernel<<<nScanB, 256, 0, stream>>>(cnt_cr, kN, off_cr, part);
  scan2_kernel<<<1, 512, 0, stream>>>(part, nScanB);
  scan3_kernel<<<nScanB, 256, 0, stream>>>(off_cr, cur_cr, part, kN);
  scatter_kernel<<<(kE + 255) / 256, 256, 0, stream>>>(dst_rc, src_rc, kE, cur_rc, perm_rc);
  scatter_kernel<<<(kE + 255) / 256, 256, 0, stream>>>(dst_cr, src_cr, kE, cur_cr, perm_cr);

  // fused attention softmax + aggregation + relu, BOTH directions in one dispatch
  // dir0: reads h_req, writes out_code (dead X region); dir1: reads h_code -> out_req
  aggregate2_kernel<<<dim3((kN + 3) / 4, 2), 256, 0, stream>>>(
      h_req, a_src_rc, a_dst_rc, perm_rc, off_rc, cnt_rc, out_code,
      h_code, a_src_cr, a_dst_cr, perm_cr, off_cr, cnt_cr, out_req);

  // BatchNorm (training-mode batch stats): two-stage, atomic-free
  bn_stats_kernel<<<dim3(kBnB, 2), 256, 0, stream>>>(out_req, out_code, bnpart);
  bn_final_kernel<<<2, 256, 0, stream>>>(bnpart, gamma, beta, sb);

  // edge dot-product classifier
  classify_kernel<<<(kEL + 3) / 4, 256, 0, stream>>>(
      out_req, out_code, el, el + kEL, sb, y, kEL);
}

// Round 8
// 716.390 us; speedup vs baseline: 1.1904x; 1.1904x over previous
//
#include <hip/hip_runtime.h>
#include <cstdint>
#include <cstddef>

namespace {

constexpr int kN    = 100000;  // nodes per type (N_REQ == N_CODE)
constexpr int kNpad = 100096;  // 782*128, GEMM tile-padded row count
constexpr int kE    = 500000;  // edges per direction
constexpr int kEL   = 200000;  // label edges
constexpr int kC    = 256;     // channels
constexpr int kH    = 8;       // heads
constexpr float kNegSlope = 0.2f;
constexpr float kBnEps    = 1e-5f;

typedef float    f32x4  __attribute__((ext_vector_type(4)));
typedef _Float16 f16x8  __attribute__((ext_vector_type(8)));
typedef _Float16 h4     __attribute__((ext_vector_type(4)));

// async global->LDS, 16 B per lane; lds base must be wave-uniform (lane*16 added by HW)
__device__ inline void async_copy16(const unsigned short* lds, const unsigned short* g) {
  __builtin_amdgcn_global_load_lds(
      (const __attribute__((address_space(1))) unsigned int*)g,
      (__attribute__((address_space(3))) unsigned int*)lds, 16, 0, 0);
}

// ------------- zero-fill (graph-capture-safe), two arrays in one dispatch -------------
__global__ void zero2_kernel(int* __restrict__ p0, int* __restrict__ p1, int n) {
  const int i = blockIdx.x * 256 + threadIdx.x;
  if (i < n) {
    p0[i] = 0;
    p1[i] = 0;
  }
}

// ------------- fp32 -> fp16 conversion (weights only, 0.25 MB each) -------------
__global__ __launch_bounds__(256) void cvt16_kernel(
    const float* __restrict__ in, _Float16* __restrict__ out, int n4) {
  const int i = blockIdx.x * 256 + threadIdx.x;
  if (i >= n4) return;
  const float4 v = ((const float4*)in)[i];
  h4 r;
  r.x = (_Float16)v.x;
  r.y = (_Float16)v.y;
  r.z = (_Float16)v.z;
  r.w = (_Float16)v.w;
  ((h4*)out)[i] = r;
}

// ------------- fused GEMM: H[M,256] = X @ W^T + b, fp16 out, BOTH node types ---------
// SINGLE-PASS FP16 MFMA in the PROVEN R5 structure (single-buffer LDS, 2 barriers
// per K-step). History: R5 split-bf16 3-pass = 191 us (MfmaUtil 17%, schedule-
// overhead-bound); R6 dbuf = 213 us (barrier vmcnt drain defeats pipelining);
// R7 LDS-free = 294 us (scattered fragment loads + per-wave W re-reads).
// fp16 (11-bit mantissa) single-pass has dot-product error ~2^-11 -- same order
// as the fp16 rounding ALREADY applied when storing h. vs R5: MFMA/3, LDS/2,
// B-traffic/2, cvt = 1 hardware cast (vs 8-op bit split), ds_reads/2.
__global__ __launch_bounds__(256) void gemm_fused_kernel(
    const float* __restrict__ X0, const float* __restrict__ X1,
    const _Float16* __restrict__ Wf0, const _Float16* __restrict__ Wf1,
    const float* __restrict__ bias0, const float* __restrict__ bias1,
    _Float16* __restrict__ H0, _Float16* __restrict__ H1) {
  __shared__ _Float16 sA[128 * 32];  // 8 KB
  __shared__ _Float16 sB[128 * 32];  // 8 KB

  const bool t1 = (blockIdx.z != 0);
  const float* __restrict__ X       = t1 ? X1 : X0;
  const _Float16* __restrict__ Wf   = t1 ? Wf1 : Wf0;
  const float* __restrict__ bias    = t1 ? bias1 : bias0;
  _Float16* __restrict__ H          = t1 ? H1 : H0;

  const int tid  = threadIdx.x;
  const int m0   = blockIdx.y * 128;
  const int n0   = blockIdx.x * 128;
  const int w    = tid >> 6, lane = tid & 63, l16 = lane & 15, quad = lane >> 4;
  const int wm   = (w >> 1) * 64, wn = (w & 1) * 64;

  // A staging: wave w covers rows w*32..+31; iter j adds j*8; lane: +lane>>3,
  // cols (lane&7)*4..+3. Padded rows (>= kN) clamp to kN-1 (stores masked later).
  const int arow = w * 32 + (lane >> 3);
  const int acol = (lane & 7) * 4;
  // B staging: wave w stages chunks 2w, 2w+1 (16 rows x 32 fp16 = 1 KB each);
  // lane L covers (row = 16j + L/4, 16B chunk L%4 -> 8 fp16) of chunk j.
  const size_t bbase = (size_t)(n0 + (lane >> 2)) * kC + (lane & 3) * 8;

  f32x4 acc[4][4] = {};

  for (int kt = 0; kt < kC / 32; ++kt) {
    const int k0 = kt * 32;
    __syncthreads();  // prior ds_reads done before overwrite
    // B: 2 async chunk copies per wave (8 chunks total)
    async_copy16((const unsigned short*)(sB + (2 * w) * 512),
                 (const unsigned short*)(Wf + bbase + (size_t)(2 * w) * 16 * kC + k0));
    async_copy16((const unsigned short*)(sB + (2 * w + 1) * 512),
                 (const unsigned short*)(Wf + bbase + (size_t)(2 * w + 1) * 16 * kC + k0));
    // A: 4 independent fp32 loads, cast to fp16, ds_write 8 B each
    f32x4 av[4];
#pragma unroll
    for (int j = 0; j < 4; ++j) {
      const int grow = min(m0 + arow + j * 8, kN - 1);
      av[j] = *(const f32x4*)&X[(size_t)grow * kC + k0 + acol];
    }
#pragma unroll
    for (int j = 0; j < 4; ++j) {
      const int row = arow + j * 8;
      h4 hv;
      hv.x = (_Float16)av[j][0];
      hv.y = (_Float16)av[j][1];
      hv.z = (_Float16)av[j][2];
      hv.w = (_Float16)av[j][3];
      *(h4*)&sA[row * 32 + acol] = hv;
    }
    __syncthreads();  // drains vmcnt (B copies) + lgkmcnt (A writes)

    f16x8 ah[4], bh[4];
#pragma unroll
    for (int mi = 0; mi < 4; ++mi) {
      const int row = wm + mi * 16 + l16;
      ah[mi] = *(const f16x8*)&sA[row * 32 + quad * 8];
    }
#pragma unroll
    for (int ni = 0; ni < 4; ++ni) {
      const int row = wn + ni * 16 + l16;
      bh[ni] = *(const f16x8*)&sB[row * 32 + quad * 8];
    }
#pragma unroll
    for (int mi = 0; mi < 4; ++mi)
#pragma unroll
      for (int ni = 0; ni < 4; ++ni)
        acc[mi][ni] = __builtin_amdgcn_mfma_f32_16x16x32_f16(ah[mi], bh[ni], acc[mi][ni], 0, 0, 0);
  }

  // epilogue: D[row=quad*4+r][col=l16] per 16x16 tile; +bias, fp16 store
#pragma unroll
  for (int ni = 0; ni < 4; ++ni) {
    const int col = n0 + wn + ni * 16 + l16;
    const float bc = bias[col];
#pragma unroll
    for (int mi = 0; mi < 4; ++mi) {
      const int gm0 = m0 + wm + mi * 16 + quad * 4;
#pragma unroll
      for (int r = 0; r < 4; ++r) {
        const int gm = gm0 + r;
        if (gm < kN) H[(size_t)gm * kC + col] = (_Float16)(acc[mi][ni][r] + bc);
      }
    }
  }
}

// ------------- per-node attention scalars: a[n,h] = <h[n,h,:], att[h,:]> -------------
__global__ __launch_bounds__(256) void avec_kernel(
    const _Float16* __restrict__ h, const float* __restrict__ attA,
    const float* __restrict__ attB, float* __restrict__ outA,
    float* __restrict__ outB, int N) {
  const int n = blockIdx.x * 4 + (threadIdx.x >> 6);
  if (n >= N) return;
  const int L = threadIdx.x & 63;
  const h4 hv = *(const h4*)&h[(size_t)n * kC + 4 * L];
  const float4 a = *(const float4*)&attA[4 * L];
  const float4 b = *(const float4*)&attB[4 * L];
  const float hx = (float)hv.x, hy = (float)hv.y, hz = (float)hv.z, hw = (float)hv.w;
  float pa = hx * a.x + hy * a.y + hz * a.z + hw * a.w;
  float pb = hx * b.x + hy * b.y + hz * b.z + hw * b.w;
  for (int m = 1; m < 8; m <<= 1) {
    pa += __shfl_xor(pa, m);
    pb += __shfl_xor(pb, m);
  }
  if ((L & 7) == 0) {
    outA[n * kH + (L >> 3)] = pa;
    outB[n * kH + (L >> 3)] = pb;
  }
}

// ------------- CSR build -------------
__global__ void count_kernel(const int* __restrict__ dst, int E, int* __restrict__ cnt) {
  const int e = blockIdx.x * 256 + threadIdx.x;
  if (e < E) atomicAdd(&cnt[dst[e]], 1);
}

__global__ void scan1_kernel(const int* __restrict__ cnt, int N,
                             int* __restrict__ off, int* __restrict__ part) {
  __shared__ int s[256];
  const int t = threadIdx.x;
  const int i = blockIdx.x * 256 + t;
  const int v = (i < N) ? cnt[i] : 0;
  s[t] = v;
  __syncthreads();
  for (int o = 1; o < 256; o <<= 1) {
    const int x = (t >= o) ? s[t - o] : 0;
    __syncthreads();
    s[t] += x;
    __syncthreads();
  }
  if (i < N) off[i] = s[t] - v;
  if (t == 255) part[blockIdx.x] = s[255];
}

__global__ void scan2_kernel(int* __restrict__ part, int NB) {  // one block, 512 thr
  __shared__ int s[512];
  const int t = threadIdx.x;
  const int v = (t < NB) ? part[t] : 0;
  s[t] = v;
  __syncthreads();
  for (int o = 1; o < 512; o <<= 1) {
    const int x = (t >= o) ? s[t - o] : 0;
    __syncthreads();
    s[t] += x;
    __syncthreads();
  }
  if (t < NB) part[t] = s[t] - v;
}

__global__ void scan3_kernel(int* __restrict__ off, int* __restrict__ cur,
                             const int* __restrict__ part, int N) {
  const int i = blockIdx.x * 256 + threadIdx.x;
  if (i < N) {
    const int v = off[i] + part[blockIdx.x];
    off[i] = v;
    cur[i] = v;
  }
}

// stores the SOURCE NODE ID (not the edge id) at the dst-sorted slot:
// aggregate then needs one less dependent indirection per edge.
__global__ void scatter_kernel(const int* __restrict__ dst,
                               const int* __restrict__ srcv, int E,
                               int* __restrict__ cur, int* __restrict__ perm) {
  const int e = blockIdx.x * 256 + threadIdx.x;
  if (e < E) {
    const int p = atomicAdd(&cur[dst[e]], 1);
    perm[p] = srcv[e];
  }
}

// ------------- fused segment-softmax + weighted aggregate + relu -------------
// Both edge directions in ONE dispatch (blockIdx.y selects), 4-way unrolled
// edge loop for memory-level parallelism. (Round-4 counters: 118.8 us,
// 4350 GB/s = 54% peak, VALU 50%, occ 71% -- mixed BW/VALU regime.)
__global__ __launch_bounds__(256) void aggregate2_kernel(
    const _Float16* __restrict__ h0, const float* __restrict__ aS0,
    const float* __restrict__ aD0, const int* __restrict__ srcs0,
    const int* __restrict__ off0, const int* __restrict__ cnt0,
    float* __restrict__ out0,
    const _Float16* __restrict__ h1, const float* __restrict__ aS1,
    const float* __restrict__ aD1, const int* __restrict__ srcs1,
    const int* __restrict__ off1, const int* __restrict__ cnt1,
    float* __restrict__ out1) {
  const int d = blockIdx.x * 4 + (threadIdx.x >> 6);
  if (d >= kN) return;
  const bool dir1 = (blockIdx.y != 0);
  const _Float16* __restrict__ hsrc = dir1 ? h1 : h0;
  const float* __restrict__ aS   = dir1 ? aS1 : aS0;
  const float* __restrict__ aD   = dir1 ? aD1 : aD0;
  const int* __restrict__ srcs   = dir1 ? srcs1 : srcs0;
  const int* __restrict__ off    = dir1 ? off1 : off0;
  const int* __restrict__ cnt    = dir1 ? cnt1 : cnt0;
  float* __restrict__ out        = dir1 ? out1 : out0;

  const int L  = threadIdx.x & 63;
  const int hd = L >> 3;  // lane's 4 channels all in head L>>3
  const float ad = aD[d * kH + hd];
  const int o = off[d], c = cnt[d];
  float4 acc = make_float4(0.f, 0.f, 0.f, 0.f);
  float se = 0.f;
  int i = 0;
  for (; i + 4 <= c; i += 4) {
    // 4 independent src ids (contiguous, cache-hot) ...
    const int s0 = srcs[o + i], s1 = srcs[o + i + 1];
    const int s2 = srcs[o + i + 2], s3 = srcs[o + i + 3];
    // ... then 4 independent scalar gathers + 4 independent row gathers
    const float a0 = aS[s0 * kH + hd], a1 = aS[s1 * kH + hd];
    const float a2 = aS[s2 * kH + hd], a3 = aS[s3 * kH + hd];
    const h4 v0 = *(const h4*)&hsrc[(size_t)s0 * kC + 4 * L];
    const h4 v1 = *(const h4*)&hsrc[(size_t)s1 * kC + 4 * L];
    const h4 v2 = *(const h4*)&hsrc[(size_t)s2 * kC + 4 * L];
    const h4 v3 = *(const h4*)&hsrc[(size_t)s3 * kC + 4 * L];
    float t0 = a0 + ad; t0 = t0 > 0.f ? t0 : kNegSlope * t0;
    float t1 = a1 + ad; t1 = t1 > 0.f ? t1 : kNegSlope * t1;
    float t2 = a2 + ad; t2 = t2 > 0.f ? t2 : kNegSlope * t2;
    float t3 = a3 + ad; t3 = t3 > 0.f ? t3 : kNegSlope * t3;
    const float w0 = __expf(t0), w1 = __expf(t1);
    const float w2 = __expf(t2), w3 = __expf(t3);
    se += (w0 + w1) + (w2 + w3);
    acc.x += w0 * (float)v0.x + w1 * (float)v1.x + w2 * (float)v2.x + w3 * (float)v3.x;
    acc.y += w0 * (float)v0.y + w1 * (float)v1.y + w2 * (float)v2.y + w3 * (float)v3.y;
    acc.z += w0 * (float)v0.z + w1 * (float)v1.z + w2 * (float)v2.z + w3 * (float)v3.z;
    acc.w += w0 * (float)v0.w + w1 * (float)v1.w + w2 * (float)v2.w + w3 * (float)v3.w;
  }
  for (; i < c; ++i) {
    const int s = srcs[o + i];
    float t = aS[s * kH + hd] + ad;
    t = t > 0.f ? t : kNegSlope * t;
    const float wgt = __expf(t);
    se += wgt;
    const h4 hv = *(const h4*)&hsrc[(size_t)s * kC + 4 * L];
    acc.x += wgt * (float)hv.x;
    acc.y += wgt * (float)hv.y;
    acc.z += wgt * (float)hv.z;
    acc.w += wgt * (float)hv.w;
  }
  const float inv = 1.f / (se + 1e-16f);
  float4 r;
  r.x = fmaxf(acc.x * inv, 0.f);
  r.y = fmaxf(acc.y * inv, 0.f);
  r.z = fmaxf(acc.z * inv, 0.f);
  r.w = fmaxf(acc.w * inv, 0.f);
  *(float4*)&out[(size_t)d * kC + 4 * L] = r;
}

// ------------- BatchNorm stats (biased var), two-stage: NO global atomics -------------
constexpr int kBnB = 512;  // blocks per tensor
__global__ __launch_bounds__(256) void bn_stats_kernel(
    const float* __restrict__ xr, const float* __restrict__ xc,
    float* __restrict__ part) {
  __shared__ f32x4 red[2][4][64];
  const float* __restrict__ x = blockIdx.y ? xc : xr;
  const int t = threadIdx.x, w = t >> 6, L = t & 63;
  const int rowsPer = (kN + kBnB - 1) / kBnB;  // 196
  const int r0 = blockIdx.x * rowsPer;
  const int r1 = min(r0 + rowsPer, kN);
  f32x4 s0 = {0.f, 0.f, 0.f, 0.f}, q0 = {0.f, 0.f, 0.f, 0.f};
  f32x4 s1 = {0.f, 0.f, 0.f, 0.f}, q1 = {0.f, 0.f, 0.f, 0.f};
  f32x4 s2 = {0.f, 0.f, 0.f, 0.f}, q2 = {0.f, 0.f, 0.f, 0.f};
  f32x4 s3 = {0.f, 0.f, 0.f, 0.f}, q3 = {0.f, 0.f, 0.f, 0.f};
  int r = r0 + w;
  for (; r + 12 < r1; r += 16) {  // 4 independent loads issued back-to-back
    const f32x4 v0 = *(const f32x4*)&x[(size_t)(r)      * kC + 4 * L];
    const f32x4 v1 = *(const f32x4*)&x[(size_t)(r + 4)  * kC + 4 * L];
    const f32x4 v2 = *(const f32x4*)&x[(size_t)(r + 8)  * kC + 4 * L];
    const f32x4 v3 = *(const f32x4*)&x[(size_t)(r + 12) * kC + 4 * L];
    s0 += v0; q0 += v0 * v0;
    s1 += v1; q1 += v1 * v1;
    s2 += v2; q2 += v2 * v2;
    s3 += v3; q3 += v3 * v3;
  }
  for (; r < r1; r += 4) {
    const f32x4 v = *(const f32x4*)&x[(size_t)r * kC + 4 * L];
    s0 += v; q0 += v * v;
  }
  const f32x4 s = (s0 + s1) + (s2 + s3);
  const f32x4 q = (q0 + q1) + (q2 + q3);
  red[0][w][L] = s;
  red[1][w][L] = q;
  __syncthreads();
  if (w == 0) {
    const f32x4 ts = red[0][0][L] + red[0][1][L] + red[0][2][L] + red[0][3][L];
    const f32x4 t2 = red[1][0][L] + red[1][1][L] + red[1][2][L] + red[1][3][L];
    float* dst = part + ((size_t)blockIdx.y * kBnB + blockIdx.x) * 512;
    *(f32x4*)&dst[4 * L]       = ts;
    *(f32x4*)&dst[256 + 4 * L] = t2;
  }
}

// Stage 2: reduce kBnB partials per channel, fold into per-channel scale/bias.
__global__ __launch_bounds__(256) void bn_final_kernel(
    const float* __restrict__ part, const float* __restrict__ gamma,
    const float* __restrict__ beta, float* __restrict__ sb) {
  const int c = threadIdx.x;
  const int t = blockIdx.x;
  const float* __restrict__ p0 = part + (size_t)t * kBnB * 512;
  float s = 0.f, q = 0.f;
#pragma unroll 4
  for (int b = 0; b < kBnB; ++b) {
    s += p0[b * 512 + c];
    q += p0[b * 512 + 256 + c];
  }
  const float mu  = s * (1.f / kN);
  const float var = q * (1.f / kN) - mu * mu;
  const float sc  = gamma[c] * rsqrtf(var + kBnEps);
  sb[t * 512 + c]       = sc;
  sb[t * 512 + 256 + c] = beta[c] - mu * sc;
}

// ------------- edge classifier: sigmoid(<z_req[i], z_code[j]>), BN fused -------------
__global__ __launch_bounds__(256) void classify_kernel(
    const float* __restrict__ zr, const float* __restrict__ zc,
    const int* __restrict__ ei, const int* __restrict__ ej,
    const float* __restrict__ sb, float* __restrict__ y, int EL) {
  const int e = blockIdx.x * 4 + (threadIdx.x >> 6);
  if (e >= EL) return;
  const int L = threadIdx.x & 63;
  const int i = ei[e], j = ej[e];
  const float4 a  = *(const float4*)&zr[(size_t)i * kC + 4 * L];
  const float4 b  = *(const float4*)&zc[(size_t)j * kC + 4 * L];
  const float4 sr = *(const float4*)&sb[4 * L];
  const float4 br = *(const float4*)&sb[256 + 4 * L];
  const float4 sc = *(const float4*)&sb[512 + 4 * L];
  const float4 bc = *(const float4*)&sb[768 + 4 * L];
  float p = (a.x * sr.x + br.x) * (b.x * sc.x + bc.x) +
            (a.y * sr.y + br.y) * (b.y * sc.y + bc.y) +
            (a.z * sr.z + br.z) * (b.z * sc.z + bc.z) +
            (a.w * sr.w + br.w) * (b.w * sc.w + bc.w);
  for (int m = 1; m < 64; m <<= 1) p += __shfl_xor(p, m);
  if (L == 0) y[e] = 1.f / (1.f + __expf(-p));
}

}  // namespace

extern "C" void kernel_launch(void* const* d_in, const int* in_sizes, int n_in,
                              void* d_out, int out_size, void* d_ws, size_t ws_size,
                              hipStream_t stream) {
  (void)in_sizes; (void)n_in; (void)out_size; (void)ws_size;
  const float* x_req      = (const float*)d_in[0];
  const float* x_code     = (const float*)d_in[1];
  const int*   ei_rc      = (const int*)d_in[2];   // [src(E) | dst(E)] req -> code
  const int*   ei_cr      = (const int*)d_in[3];   // [src(E) | dst(E)] code -> req
  const int*   el         = (const int*)d_in[4];   // [req(EL) | code(EL)]
  const float* W_req      = (const float*)d_in[5];
  const float* b_req      = (const float*)d_in[6];
  const float* W_code     = (const float*)d_in[7];
  const float* b_code     = (const float*)d_in[8];
  const float* att_src_rc = (const float*)d_in[9];
  const float* att_dst_rc = (const float*)d_in[10];
  const float* att_src_cr = (const float*)d_in[11];
  const float* att_dst_cr = (const float*)d_in[12];
  // d_in[13..15] = k_W, k_b, q : semantic attn over ONE metapath == identity -> unused
  const float* gamma      = (const float*)d_in[16];
  const float* beta       = (const float*)d_in[17];
  float* y = (float*)d_out;

  // ---- workspace (<= proven ~327 MB peak; only shrinks vs round-5 layout) ----
  char* p = (char*)d_ws;
  auto alloc = [&](size_t bytes) {
    char* r = p;
    p += (bytes + 1023) & ~(size_t)1023;
    return r;
  };
  // Former X split region kept solely as the out_code scratch (proven footprint).
  unsigned short* Xhi = (unsigned short*)alloc((size_t)kNpad * kC * 2);  // 51.25 MB
  unsigned short* Xlo = (unsigned short*)alloc((size_t)kNpad * kC * 2);  // 51.25 MB
  (void)Xlo;
  float* out_code = (float*)Xhi;  // needs 102.4 MB; region is 102.5 MB
  _Float16* h_req  = (_Float16*)alloc((size_t)kN * kC * 2);  // 51.2 MB
  _Float16* h_code = (_Float16*)alloc((size_t)kN * kC * 2);  // 51.2 MB
  float* out_req   = (float*)alloc((size_t)kN * kC * 4);     // 102.4 MB
  _Float16* Wf_r = (_Float16*)alloc((size_t)kC * kC * 2);    // 0.125 MB fp16 W
  _Float16* Wf_c = (_Float16*)alloc((size_t)kC * kC * 2);
  float* a_src_rc = (float*)alloc((size_t)kN * kH * 4);  // 3.2 MB
  float* a_dst_rc = (float*)alloc((size_t)kN * kH * 4);
  float* a_src_cr = (float*)alloc((size_t)kN * kH * 4);
  float* a_dst_cr = (float*)alloc((size_t)kN * kH * 4);
  int* cnt_rc  = (int*)alloc((size_t)kN * 4);
  int* off_rc  = (int*)alloc((size_t)kN * 4);
  int* cur_rc  = (int*)alloc((size_t)kN * 4);
  int* perm_rc = (int*)alloc((size_t)kE * 4);
  int* cnt_cr  = (int*)alloc((size_t)kN * 4);
  int* off_cr  = (int*)alloc((size_t)kN * 4);
  int* cur_cr  = (int*)alloc((size_t)kN * 4);
  int* perm_cr = (int*)alloc((size_t)kE * 4);
  int*   part  = (int*)alloc(512 * 4);
  // BN scratch aliases dead regions (proven in round 3):
  float* bnpart = (float*)a_src_rc;  // needs 2*kBnB*512*4 = 2,097,152 B (of 3.2 MB)
  float* sb     = (float*)a_src_cr;  // needs 4096 B

  const int nScanB = (kN + 255) / 256;  // 391
  const int nW4    = kC * kC / 4;       // 16384 float4

  zero2_kernel<<<nScanB, 256, 0, stream>>>(cnt_rc, cnt_cr, kN);

  // weight conversion to fp16 (tiny)
  cvt16_kernel<<<(nW4 + 255) / 256, 256, 0, stream>>>(W_req, Wf_r, nW4);
  cvt16_kernel<<<(nW4 + 255) / 256, 256, 0, stream>>>(W_code, Wf_c, nW4);

  // projections: both node types, one dispatch; fp16 single-pass MFMA
  gemm_fused_kernel<<<dim3(kC / 128, kNpad / 128, 2), 256, 0, stream>>>(
      x_req, x_code, Wf_r, Wf_c, b_req, b_code, h_req, h_code);

  // attention scalars: req is src in rc / dst in cr; code is src in cr / dst in rc
  avec_kernel<<<(kN + 3) / 4, 256, 0, stream>>>(h_req, att_src_rc, att_dst_cr,
                                                a_src_rc, a_dst_cr, kN);
  avec_kernel<<<(kN + 3) / 4, 256, 0, stream>>>(h_code, att_src_cr, att_dst_rc,
                                                a_src_cr, a_dst_rc, kN);

  // CSR build (dst-sorted src-id arrays per direction)
  const int* src_rc = ei_rc;
  const int* dst_rc = ei_rc + kE;
  const int* src_cr = ei_cr;
  const int* dst_cr = ei_cr + kE;
  count_kernel<<<(kE + 255) / 256, 256, 0, stream>>>(dst_rc, kE, cnt_rc);
  count_kernel<<<(kE + 255) / 256, 256, 0, stream>>>(dst_cr, kE, cnt_cr);
  scan1_kernel<<<nScanB, 256, 0, stream>>>(cnt_rc, kN, off_rc, part);
  scan2_kernel<<<1, 512, 0, stream>>>(part, nScanB);
  scan3_kernel<<<nScanB, 256, 0, stream>>>(off_rc, cur_rc, part, kN);
  scan1_kernel<<<nScanB, 256, 0, stream>>>(cnt_cr, kN, off_cr, part);
  scan2_kernel<<<1, 512, 0, stream>>>(part, nScanB);
  scan3_kernel<<<nScanB, 256, 0, stream>>>(off_cr, cur_cr, part, kN);
  scatter_kernel<<<(kE + 255) / 256, 256, 0, stream>>>(dst_rc, src_rc, kE, cur_rc, perm_rc);
  scatter_kernel<<<(kE + 255) / 256, 256, 0, stream>>>(dst_cr, src_cr, kE, cur_cr, perm_cr);

  // fused attention softmax + aggregation + relu, BOTH directions in one dispatch
  // dir0: reads h_req, writes out_code (dead X region); dir1: reads h_code -> out_req
  aggregate2_kernel<<<dim3((kN + 3) / 4, 2), 256, 0, stream>>>(
      h_req, a_src_rc, a_dst_rc, perm_rc, off_rc, cnt_rc, out_code,
      h_code, a_src_cr, a_dst_cr, perm_cr, off_cr, cnt_cr, out_req);

  // BatchNorm (training-mode batch stats): two-stage, atomic-free
  bn_stats_kernel<<<dim3(kBnB, 2), 256, 0, stream>>>(out_req, out_code, bnpart);
  bn_final_kernel<<<2, 256, 0, stream>>>(bnpart, gamma, beta, sb);

  // edge dot-product classifier
  classify_kernel<<<(kEL + 3) / 4, 256, 0, stream>>>(
      out_req, out_code, el, el + kEL, sb, y, kEL);
}

// Round 9
// 706.853 us; speedup vs baseline: 1.2065x; 1.0135x over previous
//
#include <hip/hip_runtime.h>
#include <cstdint>
#include <cstddef>

namespace {

constexpr int kN    = 100000;  // nodes per type (N_REQ == N_CODE)
constexpr int kNpad = 100096;  // 782*128, GEMM tile-padded row count
constexpr int kE    = 500000;  // edges per direction
constexpr int kEL   = 200000;  // label edges
constexpr int kC    = 256;     // channels
constexpr int kH    = 8;       // heads
constexpr float kNegSlope = 0.2f;
constexpr float kBnEps    = 1e-5f;

typedef float    f32x4  __attribute__((ext_vector_type(4)));
typedef _Float16 f16x8  __attribute__((ext_vector_type(8)));
typedef _Float16 h4     __attribute__((ext_vector_type(4)));

// async global->LDS, 16 B per lane; lds base must be wave-uniform (lane*16 added by HW)
__device__ inline void async_copy16(const unsigned short* lds, const unsigned short* g) {
  __builtin_amdgcn_global_load_lds(
      (const __attribute__((address_space(1))) unsigned int*)g,
      (__attribute__((address_space(3))) unsigned int*)lds, 16, 0, 0);
}

// ------------- zero-fill (graph-capture-safe), two arrays in one dispatch -------------
__global__ void zero2_kernel(int* __restrict__ p0, int* __restrict__ p1, int n) {
  const int i = blockIdx.x * 256 + threadIdx.x;
  if (i < n) {
    p0[i] = 0;
    p1[i] = 0;
  }
}

// ------------- fp32 -> fp16 conversion (weights only, 0.25 MB each) -------------
__global__ __launch_bounds__(256) void cvt16_kernel(
    const float* __restrict__ in, _Float16* __restrict__ out, int n4) {
  const int i = blockIdx.x * 256 + threadIdx.x;
  if (i >= n4) return;
  const float4 v = ((const float4*)in)[i];
  h4 r;
  r.x = (_Float16)v.x;
  r.y = (_Float16)v.y;
  r.z = (_Float16)v.z;
  r.w = (_Float16)v.w;
  ((h4*)out)[i] = r;
}

// ------------- fused GEMM: H[M,256] = X @ W^T + b, fp16 out, BOTH node types ---------
// SINGLE-PASS FP16, K-STEP 64 (two 32-wide sub-tiles per barrier pair).
// History: R5 split-bf16 = 191 us; R8 fp16 BK=32 = 158 us with MfmaUtil 6.6%,
// VALU 8.3%, HBM 33% -- nothing saturated, so ~100 us is per-K-step fixed cost
// (barrier + vmcnt/lgkm drain x 8 iters). This version halves the iteration
// count: per iter, stage BOTH sub-tiles (8 async B copies + 8 A loads), one
// barrier pair, then 2x16 MFMA. K-order identical to R8 -> bit-identical math.
__global__ __launch_bounds__(256) void gemm_fused_kernel(
    const float* __restrict__ X0, const float* __restrict__ X1,
    const _Float16* __restrict__ Wf0, const _Float16* __restrict__ Wf1,
    const float* __restrict__ bias0, const float* __restrict__ bias1,
    _Float16* __restrict__ H0, _Float16* __restrict__ H1) {
  __shared__ _Float16 sA[2][128 * 32];  // 2 x 8 KB
  __shared__ _Float16 sB[2][128 * 32];  // 2 x 8 KB

  const bool t1 = (blockIdx.z != 0);
  const float* __restrict__ X       = t1 ? X1 : X0;
  const _Float16* __restrict__ Wf   = t1 ? Wf1 : Wf0;
  const float* __restrict__ bias    = t1 ? bias1 : bias0;
  _Float16* __restrict__ H          = t1 ? H1 : H0;

  const int tid  = threadIdx.x;
  const int m0   = blockIdx.y * 128;
  const int n0   = blockIdx.x * 128;
  const int w    = tid >> 6, lane = tid & 63, l16 = lane & 15, quad = lane >> 4;
  const int wm   = (w >> 1) * 64, wn = (w & 1) * 64;

  // A staging (per sub-tile q): wave w covers rows w*32..+31; iter j adds j*8;
  // lane: +lane>>3, cols (lane&7)*4..+3. Padded rows (>= kN) clamp to kN-1.
  const int arow = w * 32 + (lane >> 3);
  const int acol = (lane & 7) * 4;
  // B staging (per sub-tile q): wave w stages chunks 2w, 2w+1 (16 rows x 1 KB);
  // lane L covers (row = 16j + L/4, 16B chunk L%4 -> 8 fp16) of chunk j.
  const size_t bbase = (size_t)(n0 + (lane >> 2)) * kC + (lane & 3) * 8;

  f32x4 acc[4][4] = {};

  for (int kt = 0; kt < kC / 64; ++kt) {  // 4 iterations
    const int k0 = kt * 64;
    __syncthreads();  // prior ds_reads done before overwrite
#pragma unroll
    for (int q = 0; q < 2; ++q) {
      const int kq = k0 + q * 32;
      async_copy16((const unsigned short*)(sB[q] + (2 * w) * 512),
                   (const unsigned short*)(Wf + bbase + (size_t)(2 * w) * 16 * kC + kq));
      async_copy16((const unsigned short*)(sB[q] + (2 * w + 1) * 512),
                   (const unsigned short*)(Wf + bbase + (size_t)(2 * w + 1) * 16 * kC + kq));
    }
    // A: 8 independent fp32x4 loads in flight, then cast + 8 B ds_writes
    f32x4 av[2][4];
#pragma unroll
    for (int q = 0; q < 2; ++q)
#pragma unroll
      for (int j = 0; j < 4; ++j) {
        const int grow = min(m0 + arow + j * 8, kN - 1);
        av[q][j] = *(const f32x4*)&X[(size_t)grow * kC + k0 + q * 32 + acol];
      }
#pragma unroll
    for (int q = 0; q < 2; ++q)
#pragma unroll
      for (int j = 0; j < 4; ++j) {
        const int row = arow + j * 8;
        h4 hv;
        hv.x = (_Float16)av[q][j][0];
        hv.y = (_Float16)av[q][j][1];
        hv.z = (_Float16)av[q][j][2];
        hv.w = (_Float16)av[q][j][3];
        *(h4*)&sA[q][row * 32 + acol] = hv;
      }
    __syncthreads();  // drains vmcnt (B copies) + lgkmcnt (A writes)

#pragma unroll
    for (int q = 0; q < 2; ++q) {
      f16x8 ah[4], bh[4];
#pragma unroll
      for (int mi = 0; mi < 4; ++mi) {
        const int row = wm + mi * 16 + l16;
        ah[mi] = *(const f16x8*)&sA[q][row * 32 + quad * 8];
      }
#pragma unroll
      for (int ni = 0; ni < 4; ++ni) {
        const int row = wn + ni * 16 + l16;
        bh[ni] = *(const f16x8*)&sB[q][row * 32 + quad * 8];
      }
#pragma unroll
      for (int mi = 0; mi < 4; ++mi)
#pragma unroll
        for (int ni = 0; ni < 4; ++ni)
          acc[mi][ni] = __builtin_amdgcn_mfma_f32_16x16x32_f16(ah[mi], bh[ni], acc[mi][ni], 0, 0, 0);
    }
  }

  // epilogue: D[row=quad*4+r][col=l16] per 16x16 tile; +bias, fp16 store
#pragma unroll
  for (int ni = 0; ni < 4; ++ni) {
    const int col = n0 + wn + ni * 16 + l16;
    const float bc = bias[col];
#pragma unroll
    for (int mi = 0; mi < 4; ++mi) {
      const int gm0 = m0 + wm + mi * 16 + quad * 4;
#pragma unroll
      for (int r = 0; r < 4; ++r) {
        const int gm = gm0 + r;
        if (gm < kN) H[(size_t)gm * kC + col] = (_Float16)(acc[mi][ni][r] + bc);
      }
    }
  }
}

// ------------- per-node attention scalars: a[n,h] = <h[n,h,:], att[h,:]> -------------
__global__ __launch_bounds__(256) void avec_kernel(
    const _Float16* __restrict__ h, const float* __restrict__ attA,
    const float* __restrict__ attB, float* __restrict__ outA,
    float* __restrict__ outB, int N) {
  const int n = blockIdx.x * 4 + (threadIdx.x >> 6);
  if (n >= N) return;
  const int L = threadIdx.x & 63;
  const h4 hv = *(const h4*)&h[(size_t)n * kC + 4 * L];
  const float4 a = *(const float4*)&attA[4 * L];
  const float4 b = *(const float4*)&attB[4 * L];
  const float hx = (float)hv.x, hy = (float)hv.y, hz = (float)hv.z, hw = (float)hv.w;
  float pa = hx * a.x + hy * a.y + hz * a.z + hw * a.w;
  float pb = hx * b.x + hy * b.y + hz * b.z + hw * b.w;
  for (int m = 1; m < 8; m <<= 1) {
    pa += __shfl_xor(pa, m);
    pb += __shfl_xor(pb, m);
  }
  if ((L & 7) == 0) {
    outA[n * kH + (L >> 3)] = pa;
    outB[n * kH + (L >> 3)] = pb;
  }
}

// ------------- CSR build -------------
__global__ void count_kernel(const int* __restrict__ dst, int E, int* __restrict__ cnt) {
  const int e = blockIdx.x * 256 + threadIdx.x;
  if (e < E) atomicAdd(&cnt[dst[e]], 1);
}

__global__ void scan1_kernel(const int* __restrict__ cnt, int N,
                             int* __restrict__ off, int* __restrict__ part) {
  __shared__ int s[256];
  const int t = threadIdx.x;
  const int i = blockIdx.x * 256 + t;
  const int v = (i < N) ? cnt[i] : 0;
  s[t] = v;
  __syncthreads();
  for (int o = 1; o < 256; o <<= 1) {
    const int x = (t >= o) ? s[t - o] : 0;
    __syncthreads();
    s[t] += x;
    __syncthreads();
  }
  if (i < N) off[i] = s[t] - v;
  if (t == 255) part[blockIdx.x] = s[255];
}

__global__ void scan2_kernel(int* __restrict__ part, int NB) {  // one block, 512 thr
  __shared__ int s[512];
  const int t = threadIdx.x;
  const int v = (t < NB) ? part[t] : 0;
  s[t] = v;
  __syncthreads();
  for (int o = 1; o < 512; o <<= 1) {
    const int x = (t >= o) ? s[t - o] : 0;
    __syncthreads();
    s[t] += x;
    __syncthreads();
  }
  if (t < NB) part[t] = s[t] - v;
}

__global__ void scan3_kernel(int* __restrict__ off, int* __restrict__ cur,
                             const int* __restrict__ part, int N) {
  const int i = blockIdx.x * 256 + threadIdx.x;
  if (i < N) {
    const int v = off[i] + part[blockIdx.x];
    off[i] = v;
    cur[i] = v;
  }
}

// stores the SOURCE NODE ID (not the edge id) at the dst-sorted slot:
// aggregate then needs one less dependent indirection per edge.
__global__ void scatter_kernel(const int* __restrict__ dst,
                               const int* __restrict__ srcv, int E,
                               int* __restrict__ cur, int* __restrict__ perm) {
  const int e = blockIdx.x * 256 + threadIdx.x;
  if (e < E) {
    const int p = atomicAdd(&cur[dst[e]], 1);
    perm[p] = srcv[e];
  }
}

// ------------- fused segment-softmax + weighted aggregate + relu -------------
// Both edge directions in ONE dispatch (blockIdx.y selects), 4-way unrolled
// edge loop for memory-level parallelism. (Round-4 counters: 118.8 us,
// 4350 GB/s = 54% peak, VALU 50%, occ 71% -- mixed BW/VALU regime.)
__global__ __launch_bounds__(256) void aggregate2_kernel(
    const _Float16* __restrict__ h0, const float* __restrict__ aS0,
    const float* __restrict__ aD0, const int* __restrict__ srcs0,
    const int* __restrict__ off0, const int* __restrict__ cnt0,
    float* __restrict__ out0,
    const _Float16* __restrict__ h1, const float* __restrict__ aS1,
    const float* __restrict__ aD1, const int* __restrict__ srcs1,
    const int* __restrict__ off1, const int* __restrict__ cnt1,
    float* __restrict__ out1) {
  const int d = blockIdx.x * 4 + (threadIdx.x >> 6);
  if (d >= kN) return;
  const bool dir1 = (blockIdx.y != 0);
  const _Float16* __restrict__ hsrc = dir1 ? h1 : h0;
  const float* __restrict__ aS   = dir1 ? aS1 : aS0;
  const float* __restrict__ aD   = dir1 ? aD1 : aD0;
  const int* __restrict__ srcs   = dir1 ? srcs1 : srcs0;
  const int* __restrict__ off    = dir1 ? off1 : off0;
  const int* __restrict__ cnt    = dir1 ? cnt1 : cnt0;
  float* __restrict__ out        = dir1 ? out1 : out0;

  const int L  = threadIdx.x & 63;
  const int hd = L >> 3;  // lane's 4 channels all in head L>>3
  const float ad = aD[d * kH + hd];
  const int o = off[d], c = cnt[d];
  float4 acc = make_float4(0.f, 0.f, 0.f, 0.f);
  float se = 0.f;
  int i = 0;
  for (; i + 4 <= c; i += 4) {
    // 4 independent src ids (contiguous, cache-hot) ...
    const int s0 = srcs[o + i], s1 = srcs[o + i + 1];
    const int s2 = srcs[o + i + 2], s3 = srcs[o + i + 3];
    // ... then 4 independent scalar gathers + 4 independent row gathers
    const float a0 = aS[s0 * kH + hd], a1 = aS[s1 * kH + hd];
    const float a2 = aS[s2 * kH + hd], a3 = aS[s3 * kH + hd];
    const h4 v0 = *(const h4*)&hsrc[(size_t)s0 * kC + 4 * L];
    const h4 v1 = *(const h4*)&hsrc[(size_t)s1 * kC + 4 * L];
    const h4 v2 = *(const h4*)&hsrc[(size_t)s2 * kC + 4 * L];
    const h4 v3 = *(const h4*)&hsrc[(size_t)s3 * kC + 4 * L];
    float t0 = a0 + ad; t0 = t0 > 0.f ? t0 : kNegSlope * t0;
    float t1 = a1 + ad; t1 = t1 > 0.f ? t1 : kNegSlope * t1;
    float t2 = a2 + ad; t2 = t2 > 0.f ? t2 : kNegSlope * t2;
    float t3 = a3 + ad; t3 = t3 > 0.f ? t3 : kNegSlope * t3;
    const float w0 = __expf(t0), w1 = __expf(t1);
    const float w2 = __expf(t2), w3 = __expf(t3);
    se += (w0 + w1) + (w2 + w3);
    acc.x += w0 * (float)v0.x + w1 * (float)v1.x + w2 * (float)v2.x + w3 * (float)v3.x;
    acc.y += w0 * (float)v0.y + w1 * (float)v1.y + w2 * (float)v2.y + w3 * (float)v3.y;
    acc.z += w0 * (float)v0.z + w1 * (float)v1.z + w2 * (float)v2.z + w3 * (float)v3.z;
    acc.w += w0 * (float)v0.w + w1 * (float)v1.w + w2 * (float)v2.w + w3 * (float)v3.w;
  }
  for (; i < c; ++i) {
    const int s = srcs[o + i];
    float t = aS[s * kH + hd] + ad;
    t = t > 0.f ? t : kNegSlope * t;
    const float wgt = __expf(t);
    se += wgt;
    const h4 hv = *(const h4*)&hsrc[(size_t)s * kC + 4 * L];
    acc.x += wgt * (float)hv.x;
    acc.y += wgt * (float)hv.y;
    acc.z += wgt * (float)hv.z;
    acc.w += wgt * (float)hv.w;
  }
  const float inv = 1.f / (se + 1e-16f);
  float4 r;
  r.x = fmaxf(acc.x * inv, 0.f);
  r.y = fmaxf(acc.y * inv, 0.f);
  r.z = fmaxf(acc.z * inv, 0.f);
  r.w = fmaxf(acc.w * inv, 0.f);
  *(float4*)&out[(size_t)d * kC + 4 * L] = r;
}

// ------------- BatchNorm stats (biased var), two-stage: NO global atomics -------------
constexpr int kBnB = 512;  // blocks per tensor
__global__ __launch_bounds__(256) void bn_stats_kernel(
    const float* __restrict__ xr, const float* __restrict__ xc,
    float* __restrict__ part) {
  __shared__ f32x4 red[2][4][64];
  const float* __restrict__ x = blockIdx.y ? xc : xr;
  const int t = threadIdx.x, w = t >> 6, L = t & 63;
  const int rowsPer = (kN + kBnB - 1) / kBnB;  // 196
  const int r0 = blockIdx.x * rowsPer;
  const int r1 = min(r0 + rowsPer, kN);
  f32x4 s0 = {0.f, 0.f, 0.f, 0.f}, q0 = {0.f, 0.f, 0.f, 0.f};
  f32x4 s1 = {0.f, 0.f, 0.f, 0.f}, q1 = {0.f, 0.f, 0.f, 0.f};
  f32x4 s2 = {0.f, 0.f, 0.f, 0.f}, q2 = {0.f, 0.f, 0.f, 0.f};
  f32x4 s3 = {0.f, 0.f, 0.f, 0.f}, q3 = {0.f, 0.f, 0.f, 0.f};
  int r = r0 + w;
  for (; r + 12 < r1; r += 16) {  // 4 independent loads issued back-to-back
    const f32x4 v0 = *(const f32x4*)&x[(size_t)(r)      * kC + 4 * L];
    const f32x4 v1 = *(const f32x4*)&x[(size_t)(r + 4)  * kC + 4 * L];
    const f32x4 v2 = *(const f32x4*)&x[(size_t)(r + 8)  * kC + 4 * L];
    const f32x4 v3 = *(const f32x4*)&x[(size_t)(r + 12) * kC + 4 * L];
    s0 += v0; q0 += v0 * v0;
    s1 += v1; q1 += v1 * v1;
    s2 += v2; q2 += v2 * v2;
    s3 += v3; q3 += v3 * v3;
  }
  for (; r < r1; r += 4) {
    const f32x4 v = *(const f32x4*)&x[(size_t)r * kC + 4 * L];
    s0 += v; q0 += v * v;
  }
  const f32x4 s = (s0 + s1) + (s2 + s3);
  const f32x4 q = (q0 + q1) + (q2 + q3);
  red[0][w][L] = s;
  red[1][w][L] = q;
  __syncthreads();
  if (w == 0) {
    const f32x4 ts = red[0][0][L] + red[0][1][L] + red[0][2][L] + red[0][3][L];
    const f32x4 t2 = red[1][0][L] + red[1][1][L] + red[1][2][L] + red[1][3][L];
    float* dst = part + ((size_t)blockIdx.y * kBnB + blockIdx.x) * 512;
    *(f32x4*)&dst[4 * L]       = ts;
    *(f32x4*)&dst[256 + 4 * L] = t2;
  }
}

// Stage 2: reduce kBnB partials per channel, fold into per-channel scale/bias.
__global__ __launch_bounds__(256) void bn_final_kernel(
    const float* __restrict__ part, const float* __restrict__ gamma,
    const float* __restrict__ beta, float* __restrict__ sb) {
  const int c = threadIdx.x;
  const int t = blockIdx.x;
  const float* __restrict__ p0 = part + (size_t)t * kBnB * 512;
  float s = 0.f, q = 0.f;
#pragma unroll 4
  for (int b = 0; b < kBnB; ++b) {
    s += p0[b * 512 + c];
    q += p0[b * 512 + 256 + c];
  }
  const float mu  = s * (1.f / kN);
  const float var = q * (1.f / kN) - mu * mu;
  const float sc  = gamma[c] * rsqrtf(var + kBnEps);
  sb[t * 512 + c]       = sc;
  sb[t * 512 + 256 + c] = beta[c] - mu * sc;
}

// ------------- edge classifier: sigmoid(<z_req[i], z_code[j]>), BN fused -------------
__global__ __launch_bounds__(256) void classify_kernel(
    const float* __restrict__ zr, const float* __restrict__ zc,
    const int* __restrict__ ei, const int* __restrict__ ej,
    const float* __restrict__ sb, float* __restrict__ y, int EL) {
  const int e = blockIdx.x * 4 + (threadIdx.x >> 6);
  if (e >= EL) return;
  const int L = threadIdx.x & 63;
  const int i = ei[e], j = ej[e];
  const float4 a  = *(const float4*)&zr[(size_t)i * kC + 4 * L];
  const float4 b  = *(const float4*)&zc[(size_t)j * kC + 4 * L];
  const float4 sr = *(const float4*)&sb[4 * L];
  const float4 br = *(const float4*)&sb[256 + 4 * L];
  const float4 sc = *(const float4*)&sb[512 + 4 * L];
  const float4 bc = *(const float4*)&sb[768 + 4 * L];
  float p = (a.x * sr.x + br.x) * (b.x * sc.x + bc.x) +
            (a.y * sr.y + br.y) * (b.y * sc.y + bc.y) +
            (a.z * sr.z + br.z) * (b.z * sc.z + bc.z) +
            (a.w * sr.w + br.w) * (b.w * sc.w + bc.w);
  for (int m = 1; m < 64; m <<= 1) p += __shfl_xor(p, m);
  if (L == 0) y[e] = 1.f / (1.f + __expf(-p));
}

}  // namespace

extern "C" void kernel_launch(void* const* d_in, const int* in_sizes, int n_in,
                              void* d_out, int out_size, void* d_ws, size_t ws_size,
                              hipStream_t stream) {
  (void)in_sizes; (void)n_in; (void)out_size; (void)ws_size;
  const float* x_req      = (const float*)d_in[0];
  const float* x_code     = (const float*)d_in[1];
  const int*   ei_rc      = (const int*)d_in[2];   // [src(E) | dst(E)] req -> code
  const int*   ei_cr      = (const int*)d_in[3];   // [src(E) | dst(E)] code -> req
  const int*   el         = (const int*)d_in[4];   // [req(EL) | code(EL)]
  const float* W_req      = (const float*)d_in[5];
  const float* b_req      = (const float*)d_in[6];
  const float* W_code     = (const float*)d_in[7];
  const float* b_code     = (const float*)d_in[8];
  const float* att_src_rc = (const float*)d_in[9];
  const float* att_dst_rc = (const float*)d_in[10];
  const float* att_src_cr = (const float*)d_in[11];
  const float* att_dst_cr = (const float*)d_in[12];
  // d_in[13..15] = k_W, k_b, q : semantic attn over ONE metapath == identity -> unused
  const float* gamma      = (const float*)d_in[16];
  const float* beta       = (const float*)d_in[17];
  float* y = (float*)d_out;

  // ---- workspace (<= proven ~327 MB peak; only shrinks vs round-5 layout) ----
  char* p = (char*)d_ws;
  auto alloc = [&](size_t bytes) {
    char* r = p;
    p += (bytes + 1023) & ~(size_t)1023;
    return r;
  };
  // Former X split region kept solely as the out_code scratch (proven footprint).
  unsigned short* Xhi = (unsigned short*)alloc((size_t)kNpad * kC * 2);  // 51.25 MB
  unsigned short* Xlo = (unsigned short*)alloc((size_t)kNpad * kC * 2);  // 51.25 MB
  (void)Xlo;
  float* out_code = (float*)Xhi;  // needs 102.4 MB; region is 102.5 MB
  _Float16* h_req  = (_Float16*)alloc((size_t)kN * kC * 2);  // 51.2 MB
  _Float16* h_code = (_Float16*)alloc((size_t)kN * kC * 2);  // 51.2 MB
  float* out_req   = (float*)alloc((size_t)kN * kC * 4);     // 102.4 MB
  _Float16* Wf_r = (_Float16*)alloc((size_t)kC * kC * 2);    // 0.125 MB fp16 W
  _Float16* Wf_c = (_Float16*)alloc((size_t)kC * kC * 2);
  float* a_src_rc = (float*)alloc((size_t)kN * kH * 4);  // 3.2 MB
  float* a_dst_rc = (float*)alloc((size_t)kN * kH * 4);
  float* a_src_cr = (float*)alloc((size_t)kN * kH * 4);
  float* a_dst_cr = (float*)alloc((size_t)kN * kH * 4);
  int* cnt_rc  = (int*)alloc((size_t)kN * 4);
  int* off_rc  = (int*)alloc((size_t)kN * 4);
  int* cur_rc  = (int*)alloc((size_t)kN * 4);
  int* perm_rc = (int*)alloc((size_t)kE * 4);
  int* cnt_cr  = (int*)alloc((size_t)kN * 4);
  int* off_cr  = (int*)alloc((size_t)kN * 4);
  int* cur_cr  = (int*)alloc((size_t)kN * 4);
  int* perm_cr = (int*)alloc((size_t)kE * 4);
  int*   part  = (int*)alloc(512 * 4);
  // BN scratch aliases dead regions (proven in round 3):
  float* bnpart = (float*)a_src_rc;  // needs 2*kBnB*512*4 = 2,097,152 B (of 3.2 MB)
  float* sb     = (float*)a_src_cr;  // needs 4096 B

  const int nScanB = (kN + 255) / 256;  // 391
  const int nW4    = kC * kC / 4;       // 16384 float4

  zero2_kernel<<<nScanB, 256, 0, stream>>>(cnt_rc, cnt_cr, kN);

  // weight conversion to fp16 (tiny)
  cvt16_kernel<<<(nW4 + 255) / 256, 256, 0, stream>>>(W_req, Wf_r, nW4);
  cvt16_kernel<<<(nW4 + 255) / 256, 256, 0, stream>>>(W_code, Wf_c, nW4);

  // projections: both node types, one dispatch; fp16 single-pass MFMA, K-step 64
  gemm_fused_kernel<<<dim3(kC / 128, kNpad / 128, 2), 256, 0, stream>>>(
      x_req, x_code, Wf_r, Wf_c, b_req, b_code, h_req, h_code);

  // attention scalars: req is src in rc / dst in cr; code is src in cr / dst in rc
  avec_kernel<<<(kN + 3) / 4, 256, 0, stream>>>(h_req, att_src_rc, att_dst_cr,
                                                a_src_rc, a_dst_cr, kN);
  avec_kernel<<<(kN + 3) / 4, 256, 0, stream>>>(h_code, att_src_cr, att_dst_rc,
                                                a_src_cr, a_dst_rc, kN);

  // CSR build (dst-sorted src-id arrays per direction)
  const int* src_rc = ei_rc;
  const int* dst_rc = ei_rc + kE;
  const int* src_cr = ei_cr;
  const int* dst_cr = ei_cr + kE;
  count_kernel<<<(kE + 255) / 256, 256, 0, stream>>>(dst_rc, kE, cnt_rc);
  count_kernel<<<(kE + 255) / 256, 256, 0, stream>>>(dst_cr, kE, cnt_cr);
  scan1_kernel<<<nScanB, 256, 0, stream>>>(cnt_rc, kN, off_rc, part);
  scan2_kernel<<<1, 512, 0, stream>>>(part, nScanB);
  scan3_kernel<<<nScanB, 256, 0, stream>>>(off_rc, cur_rc, part, kN);
  scan1_kernel<<<nScanB, 256, 0, stream>>>(cnt_cr, kN, off_cr, part);
  scan2_kernel<<<1, 512, 0, stream>>>(part, nScanB);
  scan3_kernel<<<nScanB, 256, 0, stream>>>(off_cr, cur_cr, part, kN);
  scatter_kernel<<<(kE + 255) / 256, 256, 0, stream>>>(dst_rc, src_rc, kE, cur_rc, perm_rc);
  scatter_kernel<<<(kE + 255) / 256, 256, 0, stream>>>(dst_cr, src_cr, kE, cur_cr, perm_cr);

  // fused attention softmax + aggregation + relu, BOTH directions in one dispatch
  // dir0: reads h_req, writes out_code (dead X region); dir1: reads h_code -> out_req
  aggregate2_kernel<<<dim3((kN + 3) / 4, 2), 256, 0, stream>>>(
      h_req, a_src_rc, a_dst_rc, perm_rc, off_rc, cnt_rc, out_code,
      h_code, a_src_cr, a_dst_cr, perm_cr, off_cr, cnt_cr, out_req);

  // BatchNorm (training-mode batch stats): two-stage, atomic-free
  bn_stats_kernel<<<dim3(kBnB, 2), 256, 0, stream>>>(out_req, out_code, bnpart);
  bn_final_kernel<<<2, 256, 0, stream>>>(bnpart, gamma, beta, sb);

  // edge dot-product classifier
  classify_kernel<<<(kEL + 3) / 4, 256, 0, stream>>>(
      out_req, out_code, el, el + kEL, sb, y, kEL);
}